// Round 6
// baseline (185.999 us; speedup 1.0000x reference)
//
#include <hip/hip_runtime.h>
#include <hip/hip_bf16.h>

#define NUM_CLASSES 32000
#define EMBED 128
#define NTOK (64 * 4096)
#define CLS_PER_BLK 64

typedef float f32x4 __attribute__((ext_vector_type(4)));

// ---------------------------------------------------------------------------
// Kernel 1: bias-fused transpose (all f32).
//   Wb[c*128 + e] = W[e*32000 + c] + b[e]
// Tile: 64 classes x 128 embed per block, LDS staged, stride 65 (conflict-free
// both phases). W is streamed once -> non-temporal loads. Table writes stay
// cached (the gather wants them in L2/LLC).
// ---------------------------------------------------------------------------
__global__ __launch_bounds__(256) void build_table_kernel(
    const float* __restrict__ W,
    const float* __restrict__ bias,
    float* __restrict__ Wb) {
  __shared__ float lds[EMBED * (CLS_PER_BLK + 1)];

  const int c0  = blockIdx.x * CLS_PER_BLK;
  const int tid = threadIdx.x;

  // Load phase: coalesced along classes (64 lanes x 4B = 256B rows).
  const int tx = tid & 63;   // class-in-tile
  const int ty = tid >> 6;   // 0..3
  for (int e = ty; e < EMBED; e += 4) {
    lds[e * (CLS_PER_BLK + 1) + tx] =
        __builtin_nontemporal_load(&W[(size_t)e * NUM_CLASSES + c0 + tx]);
  }
  __syncthreads();

  // Store phase: coalesced along embed (contiguous 512B f32 rows).
  const int e    = tid & 127;
  const int half = tid >> 7;  // 0..1
  const float bv = bias[e];
  for (int ci = half; ci < CLS_PER_BLK; ci += 2) {
    Wb[(size_t)(c0 + ci) * EMBED + e] = lds[e * (CLS_PER_BLK + 1) + ci] + bv;
  }
}

// ---------------------------------------------------------------------------
// Kernel 2: gather rows of Wb at (int32) token indices. 32 threads/token,
// 16B per thread. out stores are NON-TEMPORAL so the 134MB write stream
// does not evict the 16MB table from per-XCD L2.
// ---------------------------------------------------------------------------
__global__ __launch_bounds__(256) void gather_kernel(
    const int* __restrict__ x,
    const float* __restrict__ Wb,
    float* __restrict__ out) {
  const int g     = blockIdx.x * 256 + threadIdx.x;
  const int token = g >> 5;   // 32 x 16B lanes per token (128 f32)
  const int j     = g & 31;
  const int c     = x[token];
  const f32x4 v  = reinterpret_cast<const f32x4*>(Wb)[(size_t)c * 32 + j];
  __builtin_nontemporal_store(v, &reinterpret_cast<f32x4*>(out)[g]);
}

// ---------------------------------------------------------------------------
// Fallback (workspace too small): direct scattered gather from W.
// ---------------------------------------------------------------------------
__global__ __launch_bounds__(256) void direct_kernel(
    const int* __restrict__ x,
    const float* __restrict__ W,
    const float* __restrict__ bias,
    float* __restrict__ out) {
  const int g     = blockIdx.x * 256 + threadIdx.x;
  const int token = g >> 7;
  const int e     = g & 127;
  const int c     = x[token];
  out[g] = W[(size_t)e * NUM_CLASSES + c] + bias[e];
}

extern "C" void kernel_launch(void* const* d_in, const int* in_sizes, int n_in,
                              void* d_out, int out_size, void* d_ws, size_t ws_size,
                              hipStream_t stream) {
  const int*   x    = (const int*)d_in[0];
  const float* W    = (const float*)d_in[1];
  const float* bias = (const float*)d_in[2];
  float*       out  = (float*)d_out;

  const size_t table_bytes = (size_t)NUM_CLASSES * EMBED * sizeof(float);

  if (ws_size >= table_bytes) {
    float* Wb = (float*)d_ws;
    build_table_kernel<<<NUM_CLASSES / CLS_PER_BLK, 256, 0, stream>>>(W, bias, Wb);
    gather_kernel<<<(NTOK * 32) / 256, 256, 0, stream>>>(x, Wb, out);
  } else {
    direct_kernel<<<(NTOK * EMBED) / 256, 256, 0, stream>>>(x, W, bias, out);
  }
}

// Round 7
// 178.050 us; speedup vs baseline: 1.0446x; 1.0446x over previous
//
#include <hip/hip_runtime.h>
#include <hip/hip_bf16.h>

#define NUM_CLASSES 32000
#define EMBED 128
#define NTOK (64 * 4096)
#define CLS_PER_BLK 64
#define LDS_PITCH (CLS_PER_BLK + 1)

typedef float f32x4 __attribute__((ext_vector_type(4)));
typedef unsigned int u32x4 __attribute__((ext_vector_type(4)));

// round-to-nearest-even f32 -> bf16 (as uint16 in low bits)
__device__ inline unsigned int bf16_rn(float f) {
  unsigned int u = __float_as_uint(f);
  return (u + 0x7fffu + ((u >> 16) & 1u)) >> 16;
}

// ---------------------------------------------------------------------------
// Kernel 1: bias-fused transpose into a *bf16* table (8 MB, L2-friendly).
//   Wb_bf16[c*128 + e] = bf16( W[e*32000 + c] + b[e] )
// 64-class x 128-embed tile, LDS staged (pitch 65: conflict-free loads,
// 4-way on the pair-read store phase — negligible at this traffic).
// Packs e-pairs into u32 so table writes are 4B-granular coalesced.
// ---------------------------------------------------------------------------
__global__ __launch_bounds__(256) void build_table_kernel(
    const float* __restrict__ W,
    const float* __restrict__ bias,
    unsigned int* __restrict__ Wb32) {
  __shared__ float lds[EMBED * LDS_PITCH];

  const int c0  = blockIdx.x * CLS_PER_BLK;
  const int tid = threadIdx.x;

  // Load phase: coalesced along classes (64 lanes x 4B = 256B rows), nt.
  const int tx = tid & 63;   // class-in-tile
  const int ty = tid >> 6;   // 0..3
  for (int e = ty; e < EMBED; e += 4) {
    lds[e * LDS_PITCH + tx] =
        __builtin_nontemporal_load(&W[(size_t)e * NUM_CLASSES + c0 + tx]);
  }
  __syncthreads();

  // Store phase: each thread owns an e-pair (2ep, 2ep+1), packs to u32.
  const int ep  = tid & 63;   // 0..63 -> e = 2ep, 2ep+1
  const int sub = tid >> 6;   // 0..3
  const float b0 = bias[2 * ep];
  const float b1 = bias[2 * ep + 1];
  for (int ci = sub; ci < CLS_PER_BLK; ci += 4) {
    const float f0 = lds[(2 * ep) * LDS_PITCH + ci] + b0;
    const float f1 = lds[(2 * ep + 1) * LDS_PITCH + ci] + b1;
    Wb32[(size_t)(c0 + ci) * (EMBED / 2) + ep] = bf16_rn(f0) | (bf16_rn(f1) << 16);
  }
}

// ---------------------------------------------------------------------------
// Kernel 2: gather bf16 rows, expand to f32 (exact shift), nt-store out.
// 16 threads/token: 16B bf16 read + 32B f32 write per thread.
// Reads: 256B-contiguous random rows of an 8MB L2-resident table.
// Writes: 2KB contiguous per wave, non-temporal (don't thrash L2).
// ---------------------------------------------------------------------------
__global__ __launch_bounds__(256) void gather_kernel(
    const int* __restrict__ x,
    const unsigned int* __restrict__ Wb32,
    float* __restrict__ out) {
  const int g     = blockIdx.x * 256 + threadIdx.x;
  const int token = g >> 4;   // 16 lanes per token
  const int j     = g & 15;   // 16B chunk within row
  const int c     = x[token];

  const u32x4 r = reinterpret_cast<const u32x4*>(Wb32)[(size_t)c * 16 + j];

  f32x4 a, b;
  a.x = __uint_as_float(r.x << 16);
  a.y = __uint_as_float(r.x & 0xffff0000u);
  a.z = __uint_as_float(r.y << 16);
  a.w = __uint_as_float(r.y & 0xffff0000u);
  b.x = __uint_as_float(r.z << 16);
  b.y = __uint_as_float(r.z & 0xffff0000u);
  b.z = __uint_as_float(r.w << 16);
  b.w = __uint_as_float(r.w & 0xffff0000u);

  f32x4* o = reinterpret_cast<f32x4*>(out) + (size_t)g * 2;
  __builtin_nontemporal_store(a, o);
  __builtin_nontemporal_store(b, o + 1);
}

// ---------------------------------------------------------------------------
// Fallback (workspace too small): direct scattered gather from W, all f32.
// ---------------------------------------------------------------------------
__global__ __launch_bounds__(256) void direct_kernel(
    const int* __restrict__ x,
    const float* __restrict__ W,
    const float* __restrict__ bias,
    float* __restrict__ out) {
  const int g     = blockIdx.x * 256 + threadIdx.x;
  const int token = g >> 7;
  const int e     = g & 127;
  const int c     = x[token];
  out[g] = W[(size_t)e * NUM_CLASSES + c] + bias[e];
}

extern "C" void kernel_launch(void* const* d_in, const int* in_sizes, int n_in,
                              void* d_out, int out_size, void* d_ws, size_t ws_size,
                              hipStream_t stream) {
  const int*   x    = (const int*)d_in[0];
  const float* W    = (const float*)d_in[1];
  const float* bias = (const float*)d_in[2];
  float*       out  = (float*)d_out;

  const size_t table_bytes = (size_t)NUM_CLASSES * EMBED * sizeof(unsigned short);

  if (ws_size >= table_bytes) {
    unsigned int* Wb32 = (unsigned int*)d_ws;
    build_table_kernel<<<NUM_CLASSES / CLS_PER_BLK, 256, 0, stream>>>(W, bias, Wb32);
    gather_kernel<<<(NTOK * 16) / 256, 256, 0, stream>>>(x, Wb32, out);
  } else {
    direct_kernel<<<(NTOK * EMBED) / 256, 256, 0, stream>>>(x, W, bias, out);
  }
}